// Round 4
// baseline (298.547 us; speedup 1.0000x reference)
//
#include <hip/hip_runtime.h>
#include <hip/hip_bf16.h>

// GAT layer: out = h = x @ W^T  (N=200000 x 128, fp32 in / fp32 out), then
// E=500 edges: out[dst] += 0.1 * leaky_relu(attn, 0.2) * h[src].
//
// K1 history:
//   R0 LDS-W, 782 blk, no prefetch:        74.5us, 154 MB @ 2.07 TB/s
//   R2 LDS-W, 512 blk, 1-deep grid-stride: 75us,   154 MB @ 2.05 TB/s
//   R3 LDS-W, 1024 blk, 2-deep far-stride: 104us,  327 MB @ 3.17 TB/s
// Lesson: in-flight bytes/CU controls BW (R3 +55% BW). But R3's two
// per-wave streams 32 MB apart doubled the active sweep window ->
// L2/L3 thrash: WRITE 100->186 MB (partial-line writebacks), FETCH
// 50->133 MB (lost L3 x-carryover + RFO).
// R4: keep 16 KB/wave in flight, but as ONE contiguous pair of adjacent
// tiles (tiles {2p, 2p+1}); pair-stride = total waves. Single compact
// sweeping window like R0/R2, double the in-flight bytes of R2, 1024
// blocks (16 waves/CU nominal). Sequence per iteration:
//   wait -> cvtA -> cvtB (frees raws) -> issue next 16 KB -> MFMA+st A
//   -> MFMA+st B. Loads in flight across both compute/store phases.
// K2/K3 unchanged (race-free two-phase edge update).

typedef __attribute__((ext_vector_type(8))) short bf16x8;   // 8 bf16 = 4 VGPRs
typedef __attribute__((ext_vector_type(4))) float f32x4;

#define W_PAD 136   // 128 + 8 bf16; 272 B row stride; 2-way bank alias = free

__device__ __forceinline__ bf16x8 pack_bf16x8(float4 v0, float4 v1) {
  union { bf16x8 v; __hip_bfloat16 h[8]; } u;
  u.h[0] = __float2bfloat16(v0.x); u.h[1] = __float2bfloat16(v0.y);
  u.h[2] = __float2bfloat16(v0.z); u.h[3] = __float2bfloat16(v0.w);
  u.h[4] = __float2bfloat16(v1.x); u.h[5] = __float2bfloat16(v1.y);
  u.h[6] = __float2bfloat16(v1.z); u.h[7] = __float2bfloat16(v1.w);
  return u.v;
}

__global__ __launch_bounds__(256, 3) void gat_gemm_kernel(
    const float* __restrict__ x,
    const float* __restrict__ W,
    float* __restrict__ out,
    int N) {
  __shared__ __hip_bfloat16 Ws[128 * W_PAD];   // 34816 B -> 4 blocks/CU by LDS

  const int t256 = threadIdx.x;

  // Stage W (128x128 fp32 = 64 KB) into LDS as bf16, float4 loads. L2/L3-hot
  // across 1024 blocks.
  #pragma unroll
  for (int it = 0; it < 16; ++it) {
    int seg = t256 + it * 256;         // 0..4095 float4 segments
    int row = seg >> 5;                // 32 segments per 128-col row
    int off = (seg & 31) * 4;
    float4 v = *reinterpret_cast<const float4*>(&W[row * 128 + off]);
    union { ushort4 u4; __hip_bfloat16 h[4]; } wpk;
    wpk.h[0] = __float2bfloat16(v.x);
    wpk.h[1] = __float2bfloat16(v.y);
    wpk.h[2] = __float2bfloat16(v.z);
    wpk.h[3] = __float2bfloat16(v.w);
    *reinterpret_cast<ushort4*>(&Ws[row * W_PAD + off]) = wpk.u4;
  }
  __syncthreads();

  const int wave = t256 >> 6;
  const int lane = t256 & 63;
  const int m = lane & 15;     // W row (= out col) in A-frag / x row in B-frag
  const int q = lane >> 4;     // quad: k-subchunk q*8, D reg row q*4+j

  const int tiles = N >> 4;              // 16-row tiles (N % 32 == 0)
  const int npairs = tiles >> 1;         // adjacent-tile pairs
  const int gw = (int)gridDim.x * 4;     // total waves = pair stride
  int p = (int)blockIdx.x * 4 + wave;
  if (p >= npairs) return;               // wave-uniform; no barriers below

  float4 rawA[8], rawB[8];

  // Issue pair p: tiles 2p (rawA) and 2p+1 (rawB) -> 16 KB contiguous.
  {
    const float* xrA = x + (long)(2 * p * 16 + m) * 128;
    const float* xrB = xrA + 16 * 128;
    #pragma unroll
    for (int s = 0; s < 4; ++s) {
      rawA[2 * s]     = *reinterpret_cast<const float4*>(xrA + s * 32 + q * 8);
      rawA[2 * s + 1] = *reinterpret_cast<const float4*>(xrA + s * 32 + q * 8 + 4);
      rawB[2 * s]     = *reinterpret_cast<const float4*>(xrB + s * 32 + q * 8);
      rawB[2 * s + 1] = *reinterpret_cast<const float4*>(xrB + s * 32 + q * 8 + 4);
    }
  }

  while (true) {
    // Convert both tiles to bf16 fragments (frees rawA/rawB for refill).
    bf16x8 afA[4], afB[4];
    #pragma unroll
    for (int s = 0; s < 4; ++s) {
      afA[s] = pack_bf16x8(rawA[2 * s], rawA[2 * s + 1]);
      afB[s] = pack_bf16x8(rawB[2 * s], rawB[2 * s + 1]);
    }

    // Issue next pair's 16 KB now -> in flight across both MFMA+store phases.
    const int pn = p + gw;
    if (pn < npairs) {
      const float* xrA = x + (long)(2 * pn * 16 + m) * 128;
      const float* xrB = xrA + 16 * 128;
      #pragma unroll
      for (int s = 0; s < 4; ++s) {
        rawA[2 * s]     = *reinterpret_cast<const float4*>(xrA + s * 32 + q * 8);
        rawA[2 * s + 1] = *reinterpret_cast<const float4*>(xrA + s * 32 + q * 8 + 4);
        rawB[2 * s]     = *reinterpret_cast<const float4*>(xrB + s * 32 + q * 8);
        rawB[2 * s + 1] = *reinterpret_cast<const float4*>(xrB + s * 32 + q * 8 + 4);
      }
    }

    // ---- tile A = 2p ----
    {
      f32x4 acc[8];
      #pragma unroll
      for (int nt = 0; nt < 8; ++nt) acc[nt] = (f32x4){0.f, 0.f, 0.f, 0.f};
      #pragma unroll
      for (int s = 0; s < 4; ++s) {
        #pragma unroll
        for (int nt = 0; nt < 8; ++nt) {
          bf16x8 wfrag = *reinterpret_cast<const bf16x8*>(
              &Ws[(nt * 16 + m) * W_PAD + s * 32 + q * 8]);
          acc[nt] = __builtin_amdgcn_mfma_f32_16x16x32_bf16(wfrag, afA[s],
                                                            acc[nt], 0, 0, 0);
        }
      }
      float* orow = out + (long)(2 * p * 16 + m) * 128 + q * 4;
      #pragma unroll
      for (int nt = 0; nt < 8; ++nt)
        *reinterpret_cast<f32x4*>(orow + nt * 16) = acc[nt];
    }

    // ---- tile B = 2p+1 ----
    {
      f32x4 acc[8];
      #pragma unroll
      for (int nt = 0; nt < 8; ++nt) acc[nt] = (f32x4){0.f, 0.f, 0.f, 0.f};
      #pragma unroll
      for (int s = 0; s < 4; ++s) {
        #pragma unroll
        for (int nt = 0; nt < 8; ++nt) {
          bf16x8 wfrag = *reinterpret_cast<const bf16x8*>(
              &Ws[(nt * 16 + m) * W_PAD + s * 32 + q * 8]);
          acc[nt] = __builtin_amdgcn_mfma_f32_16x16x32_bf16(wfrag, afB[s],
                                                            acc[nt], 0, 0, 0);
        }
      }
      float* orow = out + (long)((2 * p + 1) * 16 + m) * 128 + q * 4;
      #pragma unroll
      for (int nt = 0; nt < 8; ++nt)
        *reinterpret_cast<f32x4*>(orow + nt * 16) = acc[nt];
    }

    if (pn >= npairs) break;
    p = pn;
  }
}

__device__ __forceinline__ int detect_i64(const int* eidx) {
  int or_odd = 0;
  #pragma unroll
  for (int k = 0; k < 16; ++k) or_odd |= eidx[2 * k + 1];
  return or_odd == 0;   // int64 little-endian: high words all zero
}

// Phase A: one block per edge. Read h rows from `out` (pure read), compute
// attn, write contribution vector 0.1*attn*h_src to ws. No races.
__global__ __launch_bounds__(128) void gat_edge_attn(
    const int* __restrict__ eidx,
    const float* __restrict__ a,       // [4, 64]
    const float* __restrict__ h,       // == out, post-GEMM
    float* __restrict__ contrib,       // [E, 128] in ws
    int E) {
  const int e = blockIdx.x;
  const int c = threadIdx.x;
  const bool is64 = detect_i64(eidx);
  const int src = is64 ? eidx[2 * e] : eidx[e];
  const int dst = is64 ? eidx[2 * (E + e)] : eidx[E + e];

  const float hs = h[(long)src * 128 + c];
  const float hd = h[(long)dst * 128 + c];

  const int head = c >> 5, d = c & 31;
  float term = a[head * 64 + d] * hs + a[head * 64 + 32 + d] * hd;
  // reduce over the 32 lanes of this head (heads occupy 32-lane halves)
  term += __shfl_xor(term, 16);
  term += __shfl_xor(term, 8);
  term += __shfl_xor(term, 4);
  term += __shfl_xor(term, 2);
  term += __shfl_xor(term, 1);
  const float attn = term >= 0.f ? term : 0.2f * term;   // leaky_relu(0.2)

  contrib[(long)e * 128 + c] = 0.1f * attn * hs;
}

// Phase B: atomic scatter-add of contributions (duplicate dst handled by HW).
__global__ __launch_bounds__(128) void gat_edge_scatter(
    const int* __restrict__ eidx,
    const float* __restrict__ contrib,
    float* __restrict__ out,
    int E) {
  const int e = blockIdx.x;
  const int c = threadIdx.x;
  const bool is64 = detect_i64(eidx);
  const int dst = is64 ? eidx[2 * (E + e)] : eidx[E + e];
  atomicAdd(&out[(long)dst * 128 + c], contrib[(long)e * 128 + c]);
}

extern "C" void kernel_launch(void* const* d_in, const int* in_sizes, int n_in,
                              void* d_out, int out_size, void* d_ws, size_t ws_size,
                              hipStream_t stream) {
  const float* x  = (const float*)d_in[0];
  const int* eidx = (const int*)d_in[1];
  const float* W  = (const float*)d_in[2];
  const float* a  = (const float*)d_in[3];
  float* out = (float*)d_out;
  float* contrib = (float*)d_ws;     // needs E*128*4 = 256 KB

  const int N = in_sizes[0] / 128;   // 200000
  const int E = in_sizes[1] / 2;     // 500

  const int tiles = N / 16;          // 12500
  const int npairs = tiles / 2;      // 6250
  int blocks = (npairs + 3) / 4;
  if (blocks > 1024) blocks = 1024;  // 4 blocks/CU, 16 waves/CU nominal
  gat_gemm_kernel<<<blocks, 256, 0, stream>>>(x, W, out, N);
  gat_edge_attn<<<E, 128, 0, stream>>>(eidx, a, out, contrib, E);
  gat_edge_scatter<<<E, 128, 0, stream>>>(eidx, contrib, out, E);
}

// Round 5
// 195.056 us; speedup vs baseline: 1.5306x; 1.5306x over previous
//
#include <hip/hip_runtime.h>
#include <hip/hip_bf16.h>

// GAT layer: out = h = x @ W^T  (N=200000 x 128, fp32 in / fp32 out), then
// E=500 edges: out[dst] += 0.1 * leaky_relu(attn, 0.2) * h[src].
//
// K1 history:
//   R0/R2 (clean): 154 MB @ 2.06 TB/s, ~75us  -- invariant across wave count
//   R3/R4 (more in-flight, scattered): 327-565 MB, L2 write amplification
// Diagnosis: every version loaded x in MFMA-fragment layout -- one float4
// instruction touches 16 rows x 512B stride = 16 scattered lines. The m13
// contiguous copy hits 6.29 TB/s on this chip; scattered per-instruction
// footprints cap at ~8 GB/s/CU and poison L2 when pushed harder.
// R5: CONTIGUOUS loads. Each block stages a 64-row x tile (32 KB) with
// 4KB-contiguous float4 instructions -> pack bf16 -> LDS; waves read MFMA
// fragments from LDS (same indexing as W, known-good). Next-tile loads are
// issued before compute and stay in flight across it: in-loop barriers are
// raw s_barrier + manual lgkmcnt(0) (no __syncthreads -> no vmcnt(0) drain).
// 768 blocks = 3/CU (LDS 52KB), 12 waves/CU, ~4 tiles/block.
// K2/K3 unchanged (race-free two-phase edge update).

typedef __attribute__((ext_vector_type(8))) short bf16x8;   // 8 bf16 = 4 VGPRs
typedef __attribute__((ext_vector_type(4))) float f32x4;

#define W_PAD 136   // 128 + 8 bf16; 272 B row stride (16B-aligned)

__global__ __launch_bounds__(256, 3) void gat_gemm_kernel(
    const float* __restrict__ x,
    const float* __restrict__ W,
    float* __restrict__ out,
    int N) {
  __shared__ __hip_bfloat16 Ws[128 * W_PAD];   // 34816 B
  __shared__ __hip_bfloat16 Xs[64 * W_PAD];    // 17408 B  (total 52224 -> 3/CU)

  const int tid = threadIdx.x;

  // Stage W (128x128 fp32 = 64 KB) into LDS as bf16. One-time per block.
  #pragma unroll
  for (int it = 0; it < 16; ++it) {
    int seg = tid + it * 256;          // 0..4095 float4 segments
    int row = seg >> 5;                // 32 segments per 128-col row
    int off = (seg & 31) * 4;
    float4 v = *reinterpret_cast<const float4*>(&W[row * 128 + off]);
    union { ushort4 u4; __hip_bfloat16 h[4]; } wpk;
    wpk.h[0] = __float2bfloat16(v.x);
    wpk.h[1] = __float2bfloat16(v.y);
    wpk.h[2] = __float2bfloat16(v.z);
    wpk.h[3] = __float2bfloat16(v.w);
    *reinterpret_cast<ushort4*>(&Ws[row * W_PAD + off]) = wpk.u4;
  }
  __syncthreads();   // one-time full sync; nothing else pending

  const int wave = tid >> 6;
  const int lane = tid & 63;
  const int m = lane & 15;     // W row (= out col) in A-frag / x row in B-frag
  const int q = lane >> 4;     // quad: k-subchunk q*8, D reg row q*4+j

  const int T64 = N >> 6;              // 64-row tiles: 200000/64 = 3125
  const int stride = (int)gridDim.x;   // 768
  int t = (int)blockIdx.x;             // block-uniform loop bounds

  // Prologue: contiguous load of tile t. Thread's float4 g = i*256+tid:
  // 256 threads x 16 B = 4 KB contiguous per instruction.
  float4 rA[8];
  {
    const float* xt = x + (long)t * 8192;      // 64*128 floats
    #pragma unroll
    for (int i = 0; i < 8; ++i)
      rA[i] = *reinterpret_cast<const float4*>(xt + (i * 256 + tid) * 4);
  }

  while (true) {
    // ---- pack rA -> Xs. float4 g covers row g>>5, cols (g&31)*4..+3. ----
    #pragma unroll
    for (int i = 0; i < 8; ++i) {
      int g = i * 256 + tid;
      union { ushort4 u4; __hip_bfloat16 h[4]; } p;
      p.h[0] = __float2bfloat16(rA[i].x);
      p.h[1] = __float2bfloat16(rA[i].y);
      p.h[2] = __float2bfloat16(rA[i].z);
      p.h[3] = __float2bfloat16(rA[i].w);
      *reinterpret_cast<ushort4*>(&Xs[(g >> 5) * W_PAD + (g & 31) * 4]) = p.u4;
    }

    // ---- issue next tile's contiguous loads: in flight across compute. ----
    const int tn = t + stride;
    if (tn < T64) {
      const float* xn = x + (long)tn * 8192;
      #pragma unroll
      for (int i = 0; i < 8; ++i)
        rA[i] = *reinterpret_cast<const float4*>(xn + (i * 256 + tid) * 4);
    }

    // LDS-only fence + raw barrier (does NOT drain vmcnt -> prefetch lives).
    asm volatile("s_waitcnt lgkmcnt(0)" ::: "memory");
    __builtin_amdgcn_sched_barrier(0);
    __builtin_amdgcn_s_barrier();

    // ---- compute: wave w handles rows w*16..w*16+15 of this tile. ----
    bf16x8 af[4];
    #pragma unroll
    for (int s = 0; s < 4; ++s)
      af[s] = *reinterpret_cast<const bf16x8*>(
          &Xs[(wave * 16 + m) * W_PAD + s * 32 + q * 8]);

    f32x4 acc[8];
    #pragma unroll
    for (int nt = 0; nt < 8; ++nt) acc[nt] = (f32x4){0.f, 0.f, 0.f, 0.f};
    #pragma unroll
    for (int s = 0; s < 4; ++s) {
      #pragma unroll
      for (int nt = 0; nt < 8; ++nt) {
        bf16x8 wfrag = *reinterpret_cast<const bf16x8*>(
            &Ws[(nt * 16 + m) * W_PAD + s * 32 + q * 8]);
        acc[nt] = __builtin_amdgcn_mfma_f32_16x16x32_bf16(wfrag, af[s],
                                                          acc[nt], 0, 0, 0);
      }
    }

    // D (reg j, lane) -> out[t*64 + w*16 + m][nt*16 + q*4 + j]
    float* orow = out + (long)(t * 64 + wave * 16 + m) * 128 + q * 4;
    #pragma unroll
    for (int nt = 0; nt < 8; ++nt)
      *reinterpret_cast<f32x4*>(orow + nt * 16) = acc[nt];

    if (tn >= T64) break;

    // Protect Xs from next iteration's writes. Own ds_reads were consumed by
    // MFMA (compiler-inserted lgkmcnt) so no extra wait needed; raw barrier
    // keeps the prefetch loads in flight.
    __builtin_amdgcn_s_barrier();
    t = tn;
  }
}

__device__ __forceinline__ int detect_i64(const int* eidx) {
  int or_odd = 0;
  #pragma unroll
  for (int k = 0; k < 16; ++k) or_odd |= eidx[2 * k + 1];
  return or_odd == 0;   // int64 little-endian: high words all zero
}

// Phase A: one block per edge. Read h rows from `out` (pure read), compute
// attn, write contribution vector 0.1*attn*h_src to ws. No races.
__global__ __launch_bounds__(128) void gat_edge_attn(
    const int* __restrict__ eidx,
    const float* __restrict__ a,       // [4, 64]
    const float* __restrict__ h,       // == out, post-GEMM
    float* __restrict__ contrib,       // [E, 128] in ws
    int E) {
  const int e = blockIdx.x;
  const int c = threadIdx.x;
  const bool is64 = detect_i64(eidx);
  const int src = is64 ? eidx[2 * e] : eidx[e];
  const int dst = is64 ? eidx[2 * (E + e)] : eidx[E + e];

  const float hs = h[(long)src * 128 + c];
  const float hd = h[(long)dst * 128 + c];

  const int head = c >> 5, d = c & 31;
  float term = a[head * 64 + d] * hs + a[head * 64 + 32 + d] * hd;
  // reduce over the 32 lanes of this head (heads occupy 32-lane halves)
  term += __shfl_xor(term, 16);
  term += __shfl_xor(term, 8);
  term += __shfl_xor(term, 4);
  term += __shfl_xor(term, 2);
  term += __shfl_xor(term, 1);
  const float attn = term >= 0.f ? term : 0.2f * term;   // leaky_relu(0.2)

  contrib[(long)e * 128 + c] = 0.1f * attn * hs;
}

// Phase B: atomic scatter-add of contributions (duplicate dst handled by HW).
__global__ __launch_bounds__(128) void gat_edge_scatter(
    const int* __restrict__ eidx,
    const float* __restrict__ contrib,
    float* __restrict__ out,
    int E) {
  const int e = blockIdx.x;
  const int c = threadIdx.x;
  const bool is64 = detect_i64(eidx);
  const int dst = is64 ? eidx[2 * (E + e)] : eidx[E + e];
  atomicAdd(&out[(long)dst * 128 + c], contrib[(long)e * 128 + c]);
}

extern "C" void kernel_launch(void* const* d_in, const int* in_sizes, int n_in,
                              void* d_out, int out_size, void* d_ws, size_t ws_size,
                              hipStream_t stream) {
  const float* x  = (const float*)d_in[0];
  const int* eidx = (const int*)d_in[1];
  const float* W  = (const float*)d_in[2];
  const float* a  = (const float*)d_in[3];
  float* out = (float*)d_out;
  float* contrib = (float*)d_ws;     // needs E*128*4 = 256 KB

  const int N = in_sizes[0] / 128;   // 200000
  const int E = in_sizes[1] / 2;     // 500

  const int T64 = N / 64;            // 3125
  int blocks = 768;                  // 3 blocks/CU (LDS-capped), 12 waves/CU
  if (blocks > T64) blocks = T64;
  gat_gemm_kernel<<<blocks, 256, 0, stream>>>(x, W, out, N);
  gat_edge_attn<<<E, 128, 0, stream>>>(eidx, a, out, contrib, E);
  gat_edge_scatter<<<E, 128, 0, stream>>>(eidx, contrib, out, E);
}

// Round 6
// 193.687 us; speedup vs baseline: 1.5414x; 1.0071x over previous
//
#include <hip/hip_runtime.h>
#include <hip/hip_bf16.h>

// GAT layer: out = h = x @ W^T  (N=200000 x 128, fp32 in / fp32 out), then
// E=500 edges: out[dst] += 0.1 * leaky_relu(attn, 0.2) * h[src].
//
// K1 evidence trail:
//   R0/R2 scattered frag loads, barrier-free:  154 MB @ 2.06 TB/s (75us)
//   R3/R4 scattered + deeper prefetch:         L2 poison, 327-565 MB, slower
//   R5 contiguous block loads + barrier convoy: 154 MB @ 2.43 TB/s (64us)
//   harness fillBuffer (contig, no sync):      6.4 TB/s on this exact setup
// Diagnosis: need BOTH contiguous per-instruction footprints (few cache
// lines per request -> outstanding-line budget goes far) AND barrier-free
// independent streams (no convoy; high duty cycle). R5 measured ~31K cycles
// per 2K-cycle iteration = block-wide barrier wait; avg in-flight ~3KB/CU
// -> exactly the observed 2.4 TB/s by Little's law.
// R6: per-WAVE pipelines. Each wave owns a 16-row x tile: contiguous loads
// (1KB/instr) -> pack bf16 -> PRIVATE per-wave LDS slice (cross-lane
// exchange within a wave: lgkmcnt(0) only, NO barrier) -> MFMA frags ->
// store. Next tile's 8KB issued before the pack: in flight across the whole
// iteration. 12 independent wave-streams/CU x 8KB >> 9KB Little's-law need.
// K2/K3 unchanged (race-free two-phase edge update).

typedef __attribute__((ext_vector_type(8))) short bf16x8;   // 8 bf16 = 4 VGPRs
typedef __attribute__((ext_vector_type(4))) float f32x4;

#define W_PAD 136   // 128 + 8 bf16; 272 B row stride (16B-aligned)

__global__ __launch_bounds__(256, 3) void gat_gemm_kernel(
    const float* __restrict__ x,
    const float* __restrict__ W,
    float* __restrict__ out,
    int N) {
  __shared__ __hip_bfloat16 Ws[128 * W_PAD];      // 34816 B
  __shared__ __hip_bfloat16 Xs[4][16 * W_PAD];    // 4 x 4352 B (per-wave slices)
  // total 52224 B -> 3 blocks/CU

  const int tid = threadIdx.x;

  // Stage W (128x128 fp32 = 64 KB) into LDS as bf16. One-time per block.
  #pragma unroll
  for (int it = 0; it < 16; ++it) {
    int seg = tid + it * 256;          // 0..4095 float4 segments
    int row = seg >> 5;                // 32 segments per 128-col row
    int off = (seg & 31) * 4;
    float4 v = *reinterpret_cast<const float4*>(&W[row * 128 + off]);
    union { ushort4 u4; __hip_bfloat16 h[4]; } wpk;
    wpk.h[0] = __float2bfloat16(v.x);
    wpk.h[1] = __float2bfloat16(v.y);
    wpk.h[2] = __float2bfloat16(v.z);
    wpk.h[3] = __float2bfloat16(v.w);
    *reinterpret_cast<ushort4*>(&Ws[row * W_PAD + off]) = wpk.u4;
  }
  __syncthreads();   // one-time; no barriers after this point

  const int wave = tid >> 6;
  const int lane = tid & 63;
  const int m = lane & 15;     // W row (= out col) in A-frag / x row in B-frag
  const int q = lane >> 4;     // quad: k-subchunk q*8, D reg row q*4+j

  __hip_bfloat16* xs = &Xs[wave][0];   // private slice: no cross-wave sharing

  const int tiles = N >> 4;              // 16-row tiles: 12500
  const int gw = (int)gridDim.x * 4;     // total waves = tile stride
  int t = (int)blockIdx.x * 4 + wave;
  if (t >= tiles) return;                // wave-uniform

  // Contiguous load of tile t: instr i covers bytes [i*1024, i*1024+1KB) of
  // the 8KB tile; lane's float4 g=i*64+lane -> row g>>5, cols (g&31)*4..+3.
  float4 raw[8];
  {
    const float* xt = x + (long)t * 2048;   // 16*128 floats
    #pragma unroll
    for (int i = 0; i < 8; ++i)
      raw[i] = *reinterpret_cast<const float4*>(xt + (i * 64 + lane) * 4);
  }

  while (true) {
    // ---- pack raw -> private LDS slice (8 x ds_write_b64). ----
    #pragma unroll
    for (int i = 0; i < 8; ++i) {
      int g = i * 64 + lane;
      union { ushort4 u4; __hip_bfloat16 h[4]; } p;
      p.h[0] = __float2bfloat16(raw[i].x);
      p.h[1] = __float2bfloat16(raw[i].y);
      p.h[2] = __float2bfloat16(raw[i].z);
      p.h[3] = __float2bfloat16(raw[i].w);
      *reinterpret_cast<ushort4*>(&xs[(g >> 5) * W_PAD + (g & 31) * 4]) = p.u4;
    }

    // ---- issue next tile's contiguous loads: in flight across compute. ----
    const int tn = t + gw;
    if (tn < tiles) {
      const float* xt = x + (long)tn * 2048;
      #pragma unroll
      for (int i = 0; i < 8; ++i)
        raw[i] = *reinterpret_cast<const float4*>(xt + (i * 64 + lane) * 4);
    }

    // Within-wave exchange fence: all 64 lanes' ds_writes complete before
    // any lane's ds_read below. Same-wave DS ops are in-order; lgkmcnt(0)
    // guarantees completion. No s_barrier -> waves stay independent.
    asm volatile("s_waitcnt lgkmcnt(0)" ::: "memory");
    __builtin_amdgcn_sched_barrier(0);

    // ---- x fragments from private slice: lane -> row m, cols s*32+q*8. ----
    bf16x8 af[4];
    #pragma unroll
    for (int s = 0; s < 4; ++s)
      af[s] = *reinterpret_cast<const bf16x8*>(
          &xs[m * W_PAD + s * 32 + q * 8]);

    f32x4 acc[8];
    #pragma unroll
    for (int nt = 0; nt < 8; ++nt) acc[nt] = (f32x4){0.f, 0.f, 0.f, 0.f};
    #pragma unroll
    for (int s = 0; s < 4; ++s) {
      #pragma unroll
      for (int nt = 0; nt < 8; ++nt) {
        bf16x8 wfrag = *reinterpret_cast<const bf16x8*>(
            &Ws[(nt * 16 + m) * W_PAD + s * 32 + q * 8]);
        acc[nt] = __builtin_amdgcn_mfma_f32_16x16x32_bf16(wfrag, af[s],
                                                          acc[nt], 0, 0, 0);
      }
    }

    // D (reg j, lane) -> out[t*16 + m][nt*16 + q*4 + j]: float4 per nt.
    float* orow = out + (long)(t * 16 + m) * 128 + q * 4;
    #pragma unroll
    for (int nt = 0; nt < 8; ++nt)
      *reinterpret_cast<f32x4*>(orow + nt * 16) = acc[nt];

    if (tn >= tiles) break;
    t = tn;
  }
}

__device__ __forceinline__ int detect_i64(const int* eidx) {
  int or_odd = 0;
  #pragma unroll
  for (int k = 0; k < 16; ++k) or_odd |= eidx[2 * k + 1];
  return or_odd == 0;   // int64 little-endian: high words all zero
}

// Phase A: one block per edge. Read h rows from `out` (pure read), compute
// attn, write contribution vector 0.1*attn*h_src to ws. No races.
__global__ __launch_bounds__(128) void gat_edge_attn(
    const int* __restrict__ eidx,
    const float* __restrict__ a,       // [4, 64]
    const float* __restrict__ h,       // == out, post-GEMM
    float* __restrict__ contrib,       // [E, 128] in ws
    int E) {
  const int e = blockIdx.x;
  const int c = threadIdx.x;
  const bool is64 = detect_i64(eidx);
  const int src = is64 ? eidx[2 * e] : eidx[e];
  const int dst = is64 ? eidx[2 * (E + e)] : eidx[E + e];

  const float hs = h[(long)src * 128 + c];
  const float hd = h[(long)dst * 128 + c];

  const int head = c >> 5, d = c & 31;
  float term = a[head * 64 + d] * hs + a[head * 64 + 32 + d] * hd;
  // reduce over the 32 lanes of this head (heads occupy 32-lane halves)
  term += __shfl_xor(term, 16);
  term += __shfl_xor(term, 8);
  term += __shfl_xor(term, 4);
  term += __shfl_xor(term, 2);
  term += __shfl_xor(term, 1);
  const float attn = term >= 0.f ? term : 0.2f * term;   // leaky_relu(0.2)

  contrib[(long)e * 128 + c] = 0.1f * attn * hs;
}

// Phase B: atomic scatter-add of contributions (duplicate dst handled by HW).
__global__ __launch_bounds__(128) void gat_edge_scatter(
    const int* __restrict__ eidx,
    const float* __restrict__ contrib,
    float* __restrict__ out,
    int E) {
  const int e = blockIdx.x;
  const int c = threadIdx.x;
  const bool is64 = detect_i64(eidx);
  const int dst = is64 ? eidx[2 * (E + e)] : eidx[E + e];
  atomicAdd(&out[(long)dst * 128 + c], contrib[(long)e * 128 + c]);
}

extern "C" void kernel_launch(void* const* d_in, const int* in_sizes, int n_in,
                              void* d_out, int out_size, void* d_ws, size_t ws_size,
                              hipStream_t stream) {
  const float* x  = (const float*)d_in[0];
  const int* eidx = (const int*)d_in[1];
  const float* W  = (const float*)d_in[2];
  const float* a  = (const float*)d_in[3];
  float* out = (float*)d_out;
  float* contrib = (float*)d_ws;     // needs E*128*4 = 256 KB

  const int N = in_sizes[0] / 128;   // 200000
  const int E = in_sizes[1] / 2;     // 500

  const int tiles = N / 16;          // 12500
  int blocks = (tiles + 3) / 4;
  if (blocks > 768) blocks = 768;    // 3 blocks/CU (LDS), 12 wave-streams/CU
  gat_gemm_kernel<<<blocks, 256, 0, stream>>>(x, W, out, N);
  gat_edge_attn<<<E, 128, 0, stream>>>(eidx, a, out, contrib, E);
  gat_edge_scatter<<<E, 128, 0, stream>>>(eidx, contrib, out, E);
}

// Round 7
// 192.251 us; speedup vs baseline: 1.5529x; 1.0075x over previous
//
#include <hip/hip_runtime.h>
#include <hip/hip_bf16.h>

// GAT layer: out = h = x @ W^T  (N=200000 x 128, fp32 in / fp32 out), then
// E=500 edges: out[dst] += 0.1 * leaky_relu(attn, 0.2) * h[src].
//
// K1 evidence trail:
//   R0/R2 scattered loads+stores:            154 MB @ 2.06 TB/s (75us)
//   R3/R4 scattered + deep prefetch:         L2 poison (write amp 1.8-3.3x)
//   R5 contiguous loads, barrier convoy:     2.43 TB/s (64us)
//   R6 contiguous loads, barrier-free waves: 2.33 TB/s (66us)  <- convoy
//      theory dead: schedule/concurrency changes don't move BW.
//   harness fillBuffer (contiguous STORES):  6.4 TB/s, same machine+moment
// The one constant across all our variants: MFMA D-layout stores scatter
// each instruction across 16 lines at 512B stride. R7 changes ONLY the
// store path: round-trip the 16x128 output tile through the per-wave LDS
// slice (reused as f32 scratch after x-frags are consumed), two 8-row
// passes: half-wave writes D-layout -> all lanes read back linear ->
// 1KB-contiguous float4 stores (same shape as the proven load path).
// Within-wave lgkmcnt ordering only; still zero in-loop barriers.
// K2/K3 unchanged (race-free two-phase edge update).

typedef __attribute__((ext_vector_type(8))) short bf16x8;   // 8 bf16 = 4 VGPRs
typedef __attribute__((ext_vector_type(4))) float f32x4;

#define W_PAD 136   // 128 + 8 bf16; 272 B row stride (16B-aligned)
#define S_PAD 132   // f32 scratch row stride (528 B): 4*(m&7) bank shift

__global__ __launch_bounds__(256, 3) void gat_gemm_kernel(
    const float* __restrict__ x,
    const float* __restrict__ W,
    float* __restrict__ out,
    int N) {
  __shared__ __hip_bfloat16 Ws[128 * W_PAD];      // 34816 B
  __shared__ __hip_bfloat16 Xs[4][16 * W_PAD];    // 4 x 4352 B (per-wave slices)
  // total 52224 B -> 3 blocks/CU; slice doubles as 8x132-f32 store scratch
  // (4224 B <= 4352 B).

  const int tid = threadIdx.x;

  // Stage W (128x128 fp32 = 64 KB) into LDS as bf16. One-time per block.
  #pragma unroll
  for (int it = 0; it < 16; ++it) {
    int seg = tid + it * 256;          // 0..4095 float4 segments
    int row = seg >> 5;                // 32 segments per 128-col row
    int off = (seg & 31) * 4;
    float4 v = *reinterpret_cast<const float4*>(&W[row * 128 + off]);
    union { ushort4 u4; __hip_bfloat16 h[4]; } wpk;
    wpk.h[0] = __float2bfloat16(v.x);
    wpk.h[1] = __float2bfloat16(v.y);
    wpk.h[2] = __float2bfloat16(v.z);
    wpk.h[3] = __float2bfloat16(v.w);
    *reinterpret_cast<ushort4*>(&Ws[row * W_PAD + off]) = wpk.u4;
  }
  __syncthreads();   // one-time; no barriers after this point

  const int wave = tid >> 6;
  const int lane = tid & 63;
  const int m = lane & 15;     // W row (= out col) in A-frag / x row in B-frag
  const int q = lane >> 4;     // quad: k-subchunk q*8, D reg row q*4+j

  __hip_bfloat16* xs = &Xs[wave][0];            // private slice
  float* xf = reinterpret_cast<float*>(xs);     // f32 view for store scratch

  const int tiles = N >> 4;              // 16-row tiles: 12500
  const int gw = (int)gridDim.x * 4;     // total waves = tile stride
  int t = (int)blockIdx.x * 4 + wave;
  if (t >= tiles) return;                // wave-uniform

  // Contiguous load of tile t: instr i covers 1 KB; lane's float4 g=i*64+lane
  // -> row g>>5, cols (g&31)*4..+3.
  float4 raw[8];
  {
    const float* xt = x + (long)t * 2048;   // 16*128 floats
    #pragma unroll
    for (int i = 0; i < 8; ++i)
      raw[i] = *reinterpret_cast<const float4*>(xt + (i * 64 + lane) * 4);
  }

  while (true) {
    // ---- pack raw -> private LDS slice (bf16, W_PAD layout). ----
    #pragma unroll
    for (int i = 0; i < 8; ++i) {
      int g = i * 64 + lane;
      union { ushort4 u4; __hip_bfloat16 h[4]; } p;
      p.h[0] = __float2bfloat16(raw[i].x);
      p.h[1] = __float2bfloat16(raw[i].y);
      p.h[2] = __float2bfloat16(raw[i].z);
      p.h[3] = __float2bfloat16(raw[i].w);
      *reinterpret_cast<ushort4*>(&xs[(g >> 5) * W_PAD + (g & 31) * 4]) = p.u4;
    }

    // ---- issue next tile's contiguous loads: in flight across compute. ----
    const int tn = t + gw;
    if (tn < tiles) {
      const float* xt = x + (long)tn * 2048;
      #pragma unroll
      for (int i = 0; i < 8; ++i)
        raw[i] = *reinterpret_cast<const float4*>(xt + (i * 64 + lane) * 4);
    }

    // Within-wave exchange fence (no s_barrier; waves stay independent).
    asm volatile("s_waitcnt lgkmcnt(0)" ::: "memory");
    __builtin_amdgcn_sched_barrier(0);

    // ---- x fragments from private slice: lane -> row m, cols s*32+q*8. ----
    bf16x8 af[4];
    #pragma unroll
    for (int s = 0; s < 4; ++s)
      af[s] = *reinterpret_cast<const bf16x8*>(
          &xs[m * W_PAD + s * 32 + q * 8]);

    f32x4 acc[8];
    #pragma unroll
    for (int nt = 0; nt < 8; ++nt) acc[nt] = (f32x4){0.f, 0.f, 0.f, 0.f};
    #pragma unroll
    for (int s = 0; s < 4; ++s) {
      #pragma unroll
      for (int nt = 0; nt < 8; ++nt) {
        bf16x8 wfrag = *reinterpret_cast<const bf16x8*>(
            &Ws[(nt * 16 + m) * W_PAD + s * 32 + q * 8]);
        acc[nt] = __builtin_amdgcn_mfma_f32_16x16x32_bf16(wfrag, af[s],
                                                          acc[nt], 0, 0, 0);
      }
    }

    // ---- coalesced store: LDS transpose in two 8-row halves. ----
    // acc (reg j, lane(m,q)) = out[t*16+m][nt*16+q*4+j]. Half h covers rows
    // m in [8h, 8h+8): half-wave writes D-layout into xf (row stride 132 ->
    // bank shift 4/row, <=4-way); then all 64 lanes read back linearly and
    // store 1KB-contiguous float4s (same shape as the load path).
    #pragma unroll
    for (int h = 0; h < 2; ++h) {
      if ((m >> 3) == h) {
        #pragma unroll
        for (int nt = 0; nt < 8; ++nt)
          *reinterpret_cast<f32x4*>(
              &xf[(m & 7) * S_PAD + nt * 16 + q * 4]) = acc[nt];
      }
      asm volatile("s_waitcnt lgkmcnt(0)" ::: "memory");
      __builtin_amdgcn_sched_barrier(0);
      float* oh = out + (long)(t * 16 + h * 8) * 128;
      #pragma unroll
      for (int i = 0; i < 4; ++i) {
        int g = i * 64 + lane;
        f32x4 v = *reinterpret_cast<const f32x4*>(
            &xf[(g >> 5) * S_PAD + (g & 31) * 4]);
        *reinterpret_cast<f32x4*>(oh + g * 4) = v;
      }
      // reads of this half must finish before next half / next pack reuses xf
      asm volatile("s_waitcnt lgkmcnt(0)" ::: "memory");
      __builtin_amdgcn_sched_barrier(0);
    }

    if (tn >= tiles) break;
    t = tn;
  }
}

__device__ __forceinline__ int detect_i64(const int* eidx) {
  int or_odd = 0;
  #pragma unroll
  for (int k = 0; k < 16; ++k) or_odd |= eidx[2 * k + 1];
  return or_odd == 0;   // int64 little-endian: high words all zero
}

// Phase A: one block per edge. Read h rows from `out` (pure read), compute
// attn, write contribution vector 0.1*attn*h_src to ws. No races.
__global__ __launch_bounds__(128) void gat_edge_attn(
    const int* __restrict__ eidx,
    const float* __restrict__ a,       // [4, 64]
    const float* __restrict__ h,       // == out, post-GEMM
    float* __restrict__ contrib,       // [E, 128] in ws
    int E) {
  const int e = blockIdx.x;
  const int c = threadIdx.x;
  const bool is64 = detect_i64(eidx);
  const int src = is64 ? eidx[2 * e] : eidx[e];
  const int dst = is64 ? eidx[2 * (E + e)] : eidx[E + e];

  const float hs = h[(long)src * 128 + c];
  const float hd = h[(long)dst * 128 + c];

  const int head = c >> 5, d = c & 31;
  float term = a[head * 64 + d] * hs + a[head * 64 + 32 + d] * hd;
  // reduce over the 32 lanes of this head (heads occupy 32-lane halves)
  term += __shfl_xor(term, 16);
  term += __shfl_xor(term, 8);
  term += __shfl_xor(term, 4);
  term += __shfl_xor(term, 2);
  term += __shfl_xor(term, 1);
  const float attn = term >= 0.f ? term : 0.2f * term;   // leaky_relu(0.2)

  contrib[(long)e * 128 + c] = 0.1f * attn * hs;
}

// Phase B: atomic scatter-add of contributions (duplicate dst handled by HW).
__global__ __launch_bounds__(128) void gat_edge_scatter(
    const int* __restrict__ eidx,
    const float* __restrict__ contrib,
    float* __restrict__ out,
    int E) {
  const int e = blockIdx.x;
  const int c = threadIdx.x;
  const bool is64 = detect_i64(eidx);
  const int dst = is64 ? eidx[2 * (E + e)] : eidx[E + e];
  atomicAdd(&out[(long)dst * 128 + c], contrib[(long)e * 128 + c]);
}

extern "C" void kernel_launch(void* const* d_in, const int* in_sizes, int n_in,
                              void* d_out, int out_size, void* d_ws, size_t ws_size,
                              hipStream_t stream) {
  const float* x  = (const float*)d_in[0];
  const int* eidx = (const int*)d_in[1];
  const float* W  = (const float*)d_in[2];
  const float* a  = (const float*)d_in[3];
  float* out = (float*)d_out;
  float* contrib = (float*)d_ws;     // needs E*128*4 = 256 KB

  const int N = in_sizes[0] / 128;   // 200000
  const int E = in_sizes[1] / 2;     // 500

  const int tiles = N / 16;          // 12500
  int blocks = (tiles + 3) / 4;
  if (blocks > 768) blocks = 768;    // 3 blocks/CU (LDS), 12 wave-streams/CU
  gat_gemm_kernel<<<blocks, 256, 0, stream>>>(x, W, out, N);
  gat_edge_attn<<<E, 128, 0, stream>>>(eidx, a, out, contrib, E);
  gat_edge_scatter<<<E, 128, 0, stream>>>(eidx, contrib, out, E);
}